// Round 6
// baseline (291.360 us; speedup 1.0000x reference)
//
#include <hip/hip_runtime.h>

#define B_ 4
#define N_ 8192
#define DIN 64
#define HDIM 64
#define DOUT 128
#define KNN 16
#define QPB 64               // queries per block (= lanes per wave)
#define PART 8               // partner waves per query block
#define NTHR (QPB * PART)    // 512 threads / block
#define CHUNK (N_ / PART)    // 1024 candidates per thread
#define CAP 16               // deferred-insert buffer slots per thread
#define CAPP 17              // padded per-lane stride (odd -> de-banked pushes)
#define BLOCKS_PER_B (N_ / QPB)  // 128

typedef float f32x4 __attribute__((ext_vector_type(4)));

// ---------------- K_prep: pack (x,y,z,sq) + compose affine params ----------------
__global__ __launch_bounds__(256) void k_prep(
    const float* __restrict__ xyz,
    const float* __restrict__ w1, const float* __restrict__ b1,
    const float* __restrict__ w2, const float* __restrict__ b2,
    const float* __restrict__ w3, const float* __restrict__ b3,
    float4* __restrict__ pk, float4* __restrict__ prm) {
  const int blk = blockIdx.x, t = threadIdx.x;
  const int b = blk >> 5;
  const int m = ((blk & 31) << 8) + t;
  const float* xb = xyz + (size_t)b * 3 * N_;
  float x = xb[m], y = xb[N_ + m], z = xb[2 * N_ + m];
  float sq = __fadd_rn(__fadd_rn(__fmul_rn(x, x), __fmul_rn(y, y)), __fmul_rn(z, z));
  pk[((size_t)b << 13) + m] = make_float4(x, y, z, sq);

  if (blk == 0) {
    __shared__ float M2[HDIM][10];
    __shared__ float bb[HDIM];
    const int o = t;
    if (o < HDIM) {
      float r[10];
#pragma unroll
      for (int c = 0; c < 10; c++) r[c] = 0.f;
      float s = b2[o];
      for (int l = 0; l < HDIM; l++) {
        float w = w2[o * HDIM + l];
#pragma unroll
        for (int c = 0; c < 10; c++) r[c] = fmaf(w, w1[l * 10 + c], r[c]);
        s = fmaf(w, b1[l], s);
      }
#pragma unroll
      for (int c = 0; c < 10; c++) M2[o][c] = r[c];
      bb[o] = s;
    }
    __syncthreads();
    if (o < HDIM) {
      float r3[10];
#pragma unroll
      for (int c = 0; c < 10; c++) r3[c] = 0.f;
      float bc = b3[o];
      for (int l = 0; l < HDIM; l++) {
        float w = w3[o * HDIM + l];
#pragma unroll
        for (int c = 0; c < 10; c++) r3[c] = fmaf(w, M2[l][c], r3[c]);
        bc = fmaf(w, bb[l], bc);
      }
      prm[o]      = make_float4(r3[0] - r3[6], r3[1] - r3[7], r3[2] - r3[8], bc);
      prm[64 + o] = make_float4(r3[3] + r3[6], r3[4] + r3[7], r3[5] + r3[8], r3[9]);
    }
  }
}

// max of 16 via v_max3-friendly triple nesting
#define MAX16(VARR, VMAX)                                                     \
  {                                                                           \
    float _m0 = fmaxf(fmaxf(VARR[0], VARR[1]), VARR[2]);                      \
    float _m1 = fmaxf(fmaxf(VARR[3], VARR[4]), VARR[5]);                      \
    float _m2 = fmaxf(fmaxf(VARR[6], VARR[7]), VARR[8]);                      \
    float _m3 = fmaxf(fmaxf(VARR[9], VARR[10]), VARR[11]);                    \
    float _m4 = fmaxf(fmaxf(VARR[12], VARR[13]), VARR[14]);                   \
    float _a = fmaxf(fmaxf(_m0, _m1), _m2);                                   \
    float _b = fmaxf(fmaxf(_m3, _m4), VARR[15]);                              \
    VMAX = fmaxf(_a, _b);                                                     \
  }

// replace-max insert into unsorted top-16 kept in registers (fully unrolled)
#define INSERT16(VARR, IARR, VMAX, DVAL, MIDX)                    \
  {                                                               \
    bool done = false;                                            \
    _Pragma("unroll") for (int _i = 0; _i < KNN; _i++) {          \
      bool hit = (!done) && (VARR[_i] == VMAX);                   \
      if (hit) { VARR[_i] = (DVAL); IARR[_i] = (MIDX); }          \
      done = done | hit;                                          \
    }                                                             \
    MAX16(VARR, VMAX);                                            \
  }

// drain deferred (d,idx) buffer -- LDS-ONLY (no global ops, so the compiler
// never emits vmcnt waits here and cannot interfere with the asm pipeline's
// counted vmcnt). Publish tau via atomicMin's returned old value.
#define FLUSH()                                                   \
  {                                                               \
    for (int c_ = 0; c_ < cnt; c_++) {                            \
      float fd_ = poolF[lbase + c_];                              \
      int fm_ = poolI[lbase + c_];                                \
      if (fd_ < vmax) { INSERT16(v, id, vmax, fd_, fm_); }        \
    }                                                             \
    cnt = 0;                                                      \
    unsigned old_ = atomicMin(&tau[q], __float_as_uint(vmax));    \
    gate = fminf(vmax, __uint_as_float(old_));                    \
  }

// issue 6 wave-uniform candidate loads on the VECTOR path (in-order vmcnt).
// EARLY-CLOBBER (=&v) destinations: the allocator may not overlap them with
// the address operands -- the async register writes can never corrupt VO/pj.
#define ISSUE6(C, VO)                                                         \
  {                                                                           \
    unsigned vo_ = (VO);                                                      \
    asm volatile(                                                             \
        "global_load_dwordx4 %0, %6, %7 offset:0\n\t"                         \
        "global_load_dwordx4 %1, %6, %7 offset:16\n\t"                        \
        "global_load_dwordx4 %2, %6, %7 offset:32\n\t"                        \
        "global_load_dwordx4 %3, %6, %7 offset:48\n\t"                        \
        "global_load_dwordx4 %4, %6, %7 offset:64\n\t"                        \
        "global_load_dwordx4 %5, %6, %7 offset:80"                            \
        : "=&v"(C[0]), "=&v"(C[1]), "=&v"(C[2]),                              \
          "=&v"(C[3]), "=&v"(C[4]), "=&v"(C[5])                               \
        : "v"(vo_), "s"(pj));                                                 \
  }

// consume one 6-candidate batch: counted in-order wait (other batch stays in
// flight), sched_barrier fences reg uses below the wait (guide rule 18).
// Filter IS the exact reference-rounded d (5 VALU + cmp):
//   d = fmaf(-2,dot,qs+cw) == (qs+cw) - 2*dot bit-exactly (2*dot exact in fp32)
#define CONSUME6(C, U0, NWAIT)                                                \
  {                                                                           \
    if (__any(cnt > CAP - 6)) { FLUSH(); }                                    \
    asm volatile("s_waitcnt vmcnt(" #NWAIT ")" ::: "memory");                 \
    __builtin_amdgcn_sched_barrier(0);                                        \
    _Pragma("unroll") for (int e = 0; e < 6; e++) {                           \
      float dot_ = fmaf(C[e].z, qz, fmaf(C[e].y, qy, __fmul_rn(C[e].x, qx))); \
      float d_ = fmaf(-2.0f, dot_, __fadd_rn(qs, C[e].w));                    \
      if (d_ < gate) {                                                        \
        poolF[lbase + cnt] = d_;                                              \
        poolI[lbase + cnt] = (unsigned short)(jC + (U0) + e);                 \
        cnt++;                                                                \
      }                                                                       \
    }                                                                         \
  }

// ---------------- K1: fused kNN + fe + shortcut + output ----------------
// block: 64 queries x 8 partner waves; wave j scans candidates [j*1024,(j+1)*1024).
// Candidate stream: asm global_load_dwordx4, wave-uniform address (one L2
// request, broadcast on return). VMEM returns IN ORDER per wave, so counted
// vmcnt(6) keeps one 6-candidate batch in flight while the previous is
// consumed -- the latency pipeline SMEM (out-of-order, lgkmcnt(0)-only)
// structurally forbids and the compiler refuses to build from HIP source.
// 168 batches exactly cover candidates 16..1023; tail peeled at vmcnt(0).
__global__ __launch_bounds__(NTHR, 4) void k_knn_fe(
    const float4* __restrict__ pk, const float4* __restrict__ prm,
    const float* __restrict__ feature, const float* __restrict__ wsM,
    const float* __restrict__ bs, float* __restrict__ out) {
  const int blk = blockIdx.x;
  const int b  = blk / BLOCKS_PER_B;
  const int n0 = (blk % BLOCKS_PER_B) * QPB;
  const int t = threadIdx.x;
  const int q = t & 63;
  const int j = __builtin_amdgcn_readfirstlane(t >> 6);  // wave-uniform partner id
  const int lbase = t * CAPP;                            // per-lane buffer base
  const size_t bb = (size_t)b << 13;

  __shared__ unsigned tau[QPB];
  __shared__ float4 prmL[2 * HDIM];
  // poolF (34.8KB): scan d-buffer [512][17] -> merge d-rows [128][64]
  //                 -> epilogue ws[128][64]
  // poolI (17.4KB): scan idx-buffer -> merge id-rows -> feature tile
  __shared__ alignas(16) float poolF[CAPP * NTHR];
  __shared__ alignas(16) unsigned short poolI[CAPP * NTHR];

  if (t < QPB) tau[t] = 0x7f800000u;  // +inf
  for (int i = t; i < 2 * HDIM; i += NTHR) prmL[i] = prm[i];

  const float4 qv = pk[bb + n0 + q];
  const float qx = qv.x, qy = qv.y, qz = qv.z, qs = qv.w;

  const float INF = __uint_as_float(0x7f800000u);
  float v[KNN]; int id[KNN];
  float vmax, gate;
  int cnt = 0;
  __syncthreads();

  const float4* pj = pk + bb + (size_t)j * CHUNK;
  const int jC = j * CHUNK;

  // prime the asm pipeline: batches 0 (cands 16..21) and 1 (22..27) in flight;
  // their ~250cy latency hides under the warm-start compute below.
  f32x4 cA[6], cB[6];
  ISSUE6(cA, 16u * 16u);
  ISSUE6(cB, 22u * 16u);

  // warm start: first 16 candidates fill the list directly with exact d
  // (compiler scalar loads -> lgkm domain only; no vmcnt interference)
  {
    float4 c[KNN];
#pragma unroll
    for (int e = 0; e < KNN; e++) c[e] = pj[e];
#pragma unroll
    for (int e = 0; e < KNN; e++) {
      float dot = fmaf(c[e].z, qz, fmaf(c[e].y, qy, __fmul_rn(c[e].x, qx)));
      v[e] = fmaf(-2.0f, dot, __fadd_rn(qs, c[e].w));  // == (qs+cw) - 2*dot exactly
      id[e] = jC + e;
    }
    MAX16(v, vmax);
    unsigned old = atomicMin(&tau[q], __float_as_uint(vmax));
    gate = fminf(vmax, __uint_as_float(old));
  }

  // steady state: 83 iterations x 2 batches; wait-then-reissue keeps exactly
  // one batch ahead in flight. u0 walks 16,28,...,1000; last loop iteration
  // issues batches 166 (u0=1012) and 167 (u0=1018).
  {
    int u0 = 16;
    for (int i = 0; i < 83; i++) {
      CONSUME6(cA, u0, 6);
      ISSUE6(cA, (unsigned)((u0 + 12) * 16));
      CONSUME6(cB, u0 + 6, 6);
      ISSUE6(cB, (unsigned)((u0 + 18) * 16));
      u0 += 12;
    }
    // tail: consume batch 166 (cA, 12 outstanding -> wait 6), then 167 (cB)
    CONSUME6(cA, u0, 6);
    CONSUME6(cB, u0 + 6, 0);
  }
  FLUSH();
  __syncthreads();

  // publish per-thread lists: rows j*16+i (ascending-m order across j)
#pragma unroll
  for (int i = 0; i < KNN; i++) {
    poolF[(j * KNN + i) * QPB + q] = v[i];
    poolI[(j * KNN + i) * QPB + q] = (unsigned short)id[i];
  }
  __syncthreads();

  float fv[KNN]; int fid[KNN]; float fm = INF;
  // stage A: wave j<4 merges partners (2j, 2j+1) -> rows (2j)*16
  if (j < 4) {
    const int l0 = (2 * j) * KNN, r1 = (2 * j + 1) * KNN;
#pragma unroll
    for (int i = 0; i < KNN; i++) {
      fv[i] = poolF[(l0 + i) * QPB + q];
      fid[i] = poolI[(l0 + i) * QPB + q];
    }
    MAX16(fv, fm);
    for (int s = 0; s < KNN; s++) {
      float d = poolF[(r1 + s) * QPB + q];
      if (d < fm) { int m_ = poolI[(r1 + s) * QPB + q]; INSERT16(fv, fid, fm, d, m_); }
    }
#pragma unroll
    for (int i = 0; i < KNN; i++) {
      poolF[(l0 + i) * QPB + q] = fv[i];
      poolI[(l0 + i) * QPB + q] = (unsigned short)fid[i];
    }
  }
  __syncthreads();
  // stage B: wave0: rows0+rows32 ; wave1: rows64+rows96 (ascending order kept)
  if (j < 2) {
    const int l0 = (4 * j) * KNN, r1 = (4 * j + 2) * KNN;
#pragma unroll
    for (int i = 0; i < KNN; i++) {
      fv[i] = poolF[(l0 + i) * QPB + q];
      fid[i] = poolI[(l0 + i) * QPB + q];
    }
    MAX16(fv, fm);
    for (int s = 0; s < KNN; s++) {
      float d = poolF[(r1 + s) * QPB + q];
      if (d < fm) { int m_ = poolI[(r1 + s) * QPB + q]; INSERT16(fv, fid, fm, d, m_); }
    }
#pragma unroll
    for (int i = 0; i < KNN; i++) {
      poolF[(l0 + i) * QPB + q] = fv[i];
      poolI[(l0 + i) * QPB + q] = (unsigned short)fid[i];
    }
  }
  __syncthreads();
  // stage C: wave0 merges rows0 + rows64 -> final ids in poolI rows 0..15
  if (j == 0) {
#pragma unroll
    for (int i = 0; i < KNN; i++) {
      fv[i] = poolF[i * QPB + q];
      fid[i] = poolI[i * QPB + q];
    }
    MAX16(fv, fm);
    for (int s = 0; s < KNN; s++) {
      float d = poolF[(4 * KNN + s) * QPB + q];
      if (d < fm) { int m_ = poolI[(4 * KNN + s) * QPB + q]; INSERT16(fv, fid, fm, d, m_); }
    }
#pragma unroll
    for (int i = 0; i < KNN; i++) poolI[i * QPB + q] = (unsigned short)fid[i];
  }
  __syncthreads();

  // gather neighbors (2 per wave-slot) into poolF rows 0..63
#pragma unroll
  for (int kk = 0; kk < 2; kk++) {
    int k = j * 2 + kk;
    int m = poolI[k * QPB + q];
    float4 c = pk[bb + m];
    float dx = __fsub_rn(c.x, qx), dy = __fsub_rn(c.y, qy), dz = __fsub_rn(c.z, qz);
    float dsq = __fadd_rn(__fadd_rn(__fmul_rn(dx, dx), __fmul_rn(dy, dy)),
                          __fmul_rn(dz, dz));
    poolF[k * QPB + q] = c.x;
    poolF[(KNN + k) * QPB + q] = c.y;
    poolF[(2 * KNN + k) * QPB + q] = c.z;
    poolF[(3 * KNN + k) * QPB + q] = dsq;
  }
  __syncthreads();

  float fo[8];
  {
    float nx[KNN], ny[KNN], nz[KNN], nd[KNN];
#pragma unroll
    for (int k = 0; k < KNN; k++) {
      nx[k] = poolF[k * QPB + q];
      ny[k] = poolF[(KNN + k) * QPB + q];
      nz[k] = poolF[(2 * KNN + k) * QPB + q];
      nd[k] = poolF[(3 * KNN + k) * QPB + q];
    }
#pragma unroll
    for (int oi = 0; oi < 8; oi++) {
      int o = j * 8 + oi;
      float4 pA = prmL[o], pB = prmL[HDIM + o];
      float basev = fmaf(qz, pA.z, fmaf(qy, pA.y, fmaf(qx, pA.x, pA.w)));
      float mx = -INF;
#pragma unroll
      for (int k = 0; k < KNN; k++) {
        float tv = fmaf(nz[k], pB.z,
                   fmaf(ny[k], pB.y,
                   fmaf(nx[k], pB.x, __fmul_rn(nd[k], pB.w))));
        mx = fmaxf(mx, tv);
      }
      fo[oi] = basev + mx;
    }
  }
  __syncthreads();  // pool free -> reuse for ws + feature tile

  // stage ws [128][64] into poolF (32 KB), feature tile [64][64] into poolI (16 KB)
  float* wsL = poolF;
  float* feL = (float*)poolI;
  for (int i = t; i < DOUT * DIN; i += NTHR) wsL[i] = wsM[i];
#pragma unroll
  for (int r = 0; r < 8; r++) {
    int c = j * 8 + r;
    feL[c * QPB + q] = feature[(size_t)(b * DIN + c) * N_ + n0 + q];
  }
  __syncthreads();

  // shortcut GEMM: wave j computes outputs o=j*8..j*8+7 and o+64 for its query q
  float acc[16];
#pragma unroll
  for (int oi = 0; oi < 16; oi++) acc[oi] = 0.f;
  for (int c4 = 0; c4 < DIN / 4; c4++) {
    float f0 = feL[(4 * c4 + 0) * QPB + q];
    float f1 = feL[(4 * c4 + 1) * QPB + q];
    float f2 = feL[(4 * c4 + 2) * QPB + q];
    float f3 = feL[(4 * c4 + 3) * QPB + q];
#pragma unroll
    for (int oi = 0; oi < 16; oi++) {
      int o = (oi < 8) ? (j * 8 + oi) : (64 + j * 8 + oi - 8);
      float4 w = ((const float4*)(wsL + o * DIN))[c4];  // wave-uniform broadcast
      acc[oi] = fmaf(w.x, f0, acc[oi]);
      acc[oi] = fmaf(w.y, f1, acc[oi]);
      acc[oi] = fmaf(w.z, f2, acc[oi]);
      acc[oi] = fmaf(w.w, f3, acc[oi]);
    }
  }
  float* ob = out + (size_t)b * DOUT * N_ + n0 + q;
#pragma unroll
  for (int oi = 0; oi < 16; oi++) {
    int o = (oi < 8) ? (j * 8 + oi) : (64 + j * 8 + oi - 8);
    ob[(size_t)o * N_] = acc[oi] + bs[o] + fo[oi & 7];
  }
}

extern "C" void kernel_launch(void* const* d_in, const int* in_sizes, int n_in,
                              void* d_out, int out_size, void* d_ws, size_t ws_size,
                              hipStream_t stream) {
  const float* xyz     = (const float*)d_in[0];
  const float* feature = (const float*)d_in[1];
  const float* w1 = (const float*)d_in[2];
  const float* b1 = (const float*)d_in[3];
  const float* w2 = (const float*)d_in[4];
  const float* b2 = (const float*)d_in[5];
  const float* w3 = (const float*)d_in[6];
  const float* b3 = (const float*)d_in[7];
  const float* wsM = (const float*)d_in[8];
  const float* bs  = (const float*)d_in[9];
  float* out = (float*)d_out;

  // workspace: [0,8KB) prm, [8KB, 8KB+512KB) packed pk
  float4* prm = (float4*)d_ws;
  float4* pkB = (float4*)((char*)d_ws + 8192);

  hipLaunchKernelGGL(k_prep, dim3(128), dim3(256), 0, stream,
                     xyz, w1, b1, w2, b2, w3, b3, pkB, prm);
  hipLaunchKernelGGL(k_knn_fe, dim3(B_ * BLOCKS_PER_B), dim3(NTHR), 0, stream,
                     pkB, prm, feature, wsM, bs, out);
}